// Round 5
// baseline (429.563 us; speedup 1.0000x reference)
//
#include <hip/hip_runtime.h>
#include <hip/hip_bf16.h>

typedef float f32x4 __attribute__((ext_vector_type(4)));
typedef unsigned int u32;
typedef u32 u32x4 __attribute__((ext_vector_type(4)));
typedef short short8 __attribute__((ext_vector_type(8)));

#define BATCH 8
#define CH    128
#define HWN   50176
#define PN    128
#define KSPLIT 32
#define KWIN  1568         // HWN / KSPLIT
#define BK    224          // fp32 k-cols per stage (896 B per row per burst)
#define NST   7            // KWIN / BK exact

__device__ __forceinline__ ushort f2bf_rn(float f){
  u32 u = __float_as_uint(f);
  u += 0x7FFFu + ((u >> 16) & 1u);
  return (ushort)(u >> 16);
}

// ---------------------------------------------------------------------------
// 256 blocks = (b, s): 128x128 partial over k-window of 1568, 8 waves.
// Wave w owns c-rows [w*16, w*16+16) x all 128 p.
// Per stage: X staged reg->LDS as packed (bf16hi<<16|bf16lo) u32, rows
// requested as 896B back-to-back bursts; M staged via __ballot into bit-LDS,
// rows requested as 7 consecutive coalesced 128B slices (896B temporal burst).
// Raw s_barrier (no vmcnt drain) keeps next-stage bursts in flight.
// ---------------------------------------------------------------------------
template<int EPI>
__global__ __launch_bounds__(512, 2)
void raggr_kernel(const float* __restrict__ X, const float* __restrict__ Mk,
                  float* __restrict__ OUT, float* __restrict__ PART){
  __shared__ u32 xtile[128*256];   // [row][64 units of 16B], unit-swizzled, 128 KB
  __shared__ u32 mbits[128*7];     // [row][7 words of 32 k-bits], 3.5 KB

  const int tid  = threadIdx.x;
  const int b    = blockIdx.x >> 5;
  const int s    = blockIdx.x & 31;
  const int lane = tid & 63;
  const int w    = tid >> 6;          // 0..7
  const int l15  = lane & 15;
  const int hi4  = lane >> 4;         // 0..3

  const size_t base = (size_t)b * CH * HWN + (size_t)s * KWIN;

  // --- X staging map: row = w*16 + (lane>>2), chunk c = lane&3 (56 floats)
  const int xrow = w*16 + (lane >> 2);
  const int xc   = lane & 3;
  const float* pXs = X + base + (size_t)xrow * HWN + xc*56;
  u32* xw = xtile + xrow*256;
  const int rx15 = xrow & 15;

  // --- M staging map: iter i in [0,56): row = w*16 + 2*(i/7) + (lane>>5),
  //     float col = (i%7)*32 + (lane&31)   (coalesced 128B slice per row-half)
  const float* pMs = Mk + base + (size_t)(w*16 + (lane >> 5)) * HWN + (lane & 31);

  // --- compute-side A read base (lane's own C row)
  const int arow = w*16 + l15;
  const u32* xrd = xtile + arow*256;
  const int ra15 = arow & 15;

  f32x4 xv[14];
  float mv[56];
  f32x4 acc[8];
  #pragma unroll
  for(int n=0;n<8;++n) acc[n] = (f32x4){0.f,0.f,0.f,0.f};

  #define XISSUE(t) { _Pragma("unroll")                                       \
    for(int i=0;i<14;++i)                                                     \
      xv[i] = *(const f32x4*)(pXs + (size_t)(t)*BK + i*4); }

  #define MISSUE(t) { _Pragma("unroll")                                       \
    for(int i=0;i<56;++i)                                                     \
      mv[i] = *(const float*)(pMs + (size_t)(2*(i/7))*HWN + (size_t)(t)*BK + (i%7)*32); }

  #define XWRITE() { _Pragma("unroll")                                        \
    for(int i=0;i<14;++i){                                                    \
      u32x4 wd;                                                               \
      _Pragma("unroll")                                                       \
      for(int j=0;j<4;++j){                                                   \
        float f = xv[i][j];                                                   \
        u32 uu = __float_as_uint(f);                                          \
        u32 hb = uu & 0xFFFF0000u;                                            \
        wd[j] = hb | (u32)f2bf_rn(f - __uint_as_float(hb));                   \
      }                                                                       \
      *(u32x4*)(xw + (((xc*14 + i) ^ rx15) << 2)) = wd;                       \
    } }

  #define MWRITE() { _Pragma("unroll")                                        \
    for(int i=0;i<56;++i){                                                    \
      unsigned long long bal = __ballot(mv[i] != 0.0f);                       \
      if((lane & 31) == 0)                                                    \
        mbits[(w*16 + 2*(i/7) + (lane>>5))*7 + (i%7)] = (u32)(bal >> ((lane>>5)*32)); \
    } }

  #define COMPUTE() { _Pragma("unroll")                                       \
    for(int ks=0;ks<7;++ks){                                                  \
      u32x4 w0 = *(const u32x4*)(xrd + (((ks*8 + hi4*2    ) ^ ra15) << 2));   \
      u32x4 w1 = *(const u32x4*)(xrd + (((ks*8 + hi4*2 + 1) ^ ra15) << 2));   \
      union{ short8 v; u32 u[4]; } ah, al;                                    \
      ah.u[0] = (w0[0]>>16) | (w0[1]&0xFFFF0000u);  al.u[0] = (w0[0]&0xFFFFu) | (w0[1]<<16); \
      ah.u[1] = (w0[2]>>16) | (w0[3]&0xFFFF0000u);  al.u[1] = (w0[2]&0xFFFFu) | (w0[3]<<16); \
      ah.u[2] = (w1[0]>>16) | (w1[1]&0xFFFF0000u);  al.u[2] = (w1[0]&0xFFFFu) | (w1[1]<<16); \
      ah.u[3] = (w1[2]>>16) | (w1[3]&0xFFFF0000u);  al.u[3] = (w1[2]&0xFFFFu) | (w1[3]<<16); \
      _Pragma("unroll")                                                       \
      for(int n=0;n<8;++n){                                                   \
        u32 byt = (mbits[(n*16+l15)*7 + ks] >> (hi4*8)) & 0xFFu;              \
        union{ short8 v; u32 u[4]; } bfr;                                     \
        _Pragma("unroll")                                                     \
        for(int j=0;j<4;++j){                                                 \
          u32 t2 = byt >> (2*j);                                              \
          bfr.u[j] = ((t2 & 1u) ? 0x00003F80u : 0u) | ((t2 & 2u) ? 0x3F800000u : 0u); \
        }                                                                     \
        acc[n] = __builtin_amdgcn_mfma_f32_16x16x32_bf16(ah.v, bfr.v, acc[n], 0,0,0); \
        acc[n] = __builtin_amdgcn_mfma_f32_16x16x32_bf16(al.v, bfr.v, acc[n], 0,0,0); \
      }                                                                       \
    } }

  XISSUE(0); MISSUE(0);

  #pragma unroll 1
  for(int t=0; t<NST; ++t){
    XWRITE();                         // compiler waits xv loads (vmcnt tracks)
    MWRITE();                         // compiler waits mv loads
    if(t+1 < NST){ XISSUE(t+1); MISSUE(t+1); }   // bursts stay in flight past barrier
    asm volatile("s_waitcnt lgkmcnt(0)" ::: "memory");   // LDS writes visible
    __builtin_amdgcn_s_barrier();
    __builtin_amdgcn_sched_barrier(0);
    COMPUTE();
    __builtin_amdgcn_s_barrier();     // reads consumed before next overwrite
    __builtin_amdgcn_sched_barrier(0);
  }

  // epilogue — C/D layout: col=lane&15, row=(lane>>4)*4+j  [m89]
  if(EPI == 0){
    // PART layout [b][c][s][p]
    #pragma unroll
    for(int n=0;n<8;++n){
      int col  = n*16 + l15;
      int row0 = w*16 + hi4*4;
      #pragma unroll
      for(int j=0;j<4;++j)
        PART[(size_t)b*524288 + (size_t)(row0+j)*4096 + s*128 + col] = acc[n][j];
    }
  } else {
    float* o = OUT + (size_t)b * 16384;
    #pragma unroll
    for(int n=0;n<8;++n){
      int col  = n*16 + l15;
      int row0 = w*16 + hi4*4;
      #pragma unroll
      for(int j=0;j<4;++j) atomicAdd(&o[(size_t)(row0+j)*128 + col], acc[n][j]);
    }
  }
  #undef XISSUE
  #undef MISSUE
  #undef XWRITE
  #undef MWRITE
  #undef COMPUTE
}

// out[b][c][p] = sum_s PART[b][c][s][p] — fully coalesced reads.
__global__ void reduce_kernel(const float* __restrict__ PART, float* __restrict__ OUT){
  int bid = blockIdx.x;                          // 0..511
  int b   = bid >> 6;
  int c   = (bid & 63)*2 + (threadIdx.x >> 7);   // 0..127
  int p   = threadIdx.x & 127;
  size_t base_ = (size_t)b*524288 + (size_t)c*4096 + p;
  float sum = 0.f;
  #pragma unroll 8
  for(int k=0;k<32;++k) sum += PART[base_ + k*128];
  OUT[(size_t)b*16384 + c*128 + p] = sum;
}

__global__ void zero_kernel(float* __restrict__ OUT){
  int idx = blockIdx.x * 256 + threadIdx.x;
  if(idx < BATCH*CH*PN) OUT[idx] = 0.f;
}

extern "C" void kernel_launch(void* const* d_in, const int* in_sizes, int n_in,
                              void* d_out, int out_size, void* d_ws, size_t ws_size,
                              hipStream_t stream){
  const float* X  = (const float*)d_in[0];
  const float* Mk = (const float*)d_in[1];
  float* O = (float*)d_out;

  const size_t part_bytes = (size_t)BATCH * KSPLIT * CH * PN * sizeof(float); // 16.8 MB
  if(ws_size >= part_bytes && d_ws != nullptr){
    float* part = (float*)d_ws;
    raggr_kernel<0><<<dim3(BATCH*KSPLIT), dim3(512), 0, stream>>>(X, Mk, O, part);
    reduce_kernel<<<dim3(512), dim3(256), 0, stream>>>(part, O);
  } else {
    zero_kernel<<<dim3(512), dim3(256), 0, stream>>>(O);
    raggr_kernel<1><<<dim3(BATCH*KSPLIT), dim3(512), 0, stream>>>(X, Mk, O, nullptr);
  }
}